// Round 6
// baseline (146.916 us; speedup 1.0000x reference)
//
#include <hip/hip_runtime.h>

// Problem constants
#define H   16
#define E   300
#define D   768
#define HD  48
#define QL  64
#define KL  64
#define NH  64          // n(4) * h(16)
#define ROWS 384        // 256 Q rows + 64 K + 64 V
#define NEG 8           // e-chunk count
#define ECH 38          // e per mega block (last block: 34)

// Workspace float offsets
#define OFF_PF 0                              // Pf[384][768]
#define OFF_OP (ROWS*D)                       // 294,912   OP[8][nh][q][48]
#define OFF_TICK (OFF_OP + NEG*NH*QL*48)      // 1,867,776 64 uint tickets
// end ~ 7.5 MB

// ---------------------------------------------------------------------------
// K1: single-pass QKV projection + bias -> Pf.  BM=32, BN=64, BK=64, K=768.
// grid (12 rowblk, 12 colblk) = 144 blocks, 256 thr, 4x2 microtile.
// Replaces splitK proj + reduce (kills the 27 MB PP round-trip + one node).
// LDS reads: X is 2-addr broadcast per wave, W is 2-way -> conflict-free.
// ---------------------------------------------------------------------------
__global__ __launch_bounds__(256, 2) void projPf_kernel(
    const float* __restrict__ qin, const float* __restrict__ kin, const float* __restrict__ vin,
    const float* __restrict__ Wq, const float* __restrict__ Wk, const float* __restrict__ Wv,
    const float* __restrict__ bq, const float* __restrict__ bk, const float* __restrict__ bv,
    float* __restrict__ ws)
{
    const int bx = blockIdx.x;                // rowblk 0..11 (32 rows each)
    const int by = blockIdx.y;                // colblk 0..11 (64 cols each)

    // rowblk 0..7 -> Q, 8..9 -> K, 10..11 -> V (32-row blocks never straddle)
    const float* W    = (bx < 8) ? Wq : (bx < 10) ? Wk : Wv;
    const float* bias = (bx < 8) ? bq : (bx < 10) ? bk : bv;

    __shared__ float XsT[64][36];             // [dk][row], 36: 144B rows (16B-mult)
    __shared__ float Ws[64][64];              // [dk][col]

    const int tid = threadIdx.x;
    const int r0  = (tid >> 5) * 4;           // 0..28 (8 row-groups of 4)
    const int c0  = (tid & 31) * 2;           // 0..62 (32 col-groups of 2)

    float acc[4][2];
    #pragma unroll
    for (int i = 0; i < 4; i++) { acc[i][0] = 0.f; acc[i][1] = 0.f; }

    for (int kb = 0; kb < D; kb += 64) {
        // stage X tile (32 rows x 64 dk), transposed
        #pragma unroll
        for (int it = 0; it < 2; it++) {
            const int idx = it * 256 + tid;   // 0..511
            const int row = idx >> 4;         // 0..31
            const int d4  = (idx & 15) * 4;   // 0..60
            const int grow = bx * 32 + row;
            const float* src = (grow < 256) ? (qin + grow * D)
                             : (grow < 320) ? (kin + (grow - 256) * D)
                                            : (vin + (grow - 320) * D);
            const float4 xv = *(const float4*)(src + kb + d4);
            XsT[d4 + 0][row] = xv.x; XsT[d4 + 1][row] = xv.y;
            XsT[d4 + 2][row] = xv.z; XsT[d4 + 3][row] = xv.w;
        }
        // stage W tile (64 dk x 64 cols)
        #pragma unroll
        for (int it = 0; it < 4; it++) {
            const int idx = it * 256 + tid;   // 0..1023
            const int dk  = idx >> 4;         // 0..63
            const int c4  = (idx & 15) * 4;   // 0..60
            *(float4*)&Ws[dk][c4] =
                *(const float4*)(W + (kb + dk) * D + by * 64 + c4);
        }
        __syncthreads();
        #pragma unroll 16
        for (int dk = 0; dk < 64; dk++) {
            const float4 x4 = *(const float4*)&XsT[dk][r0];
            const float2 w2 = *(const float2*)&Ws[dk][c0];
            acc[0][0] = fmaf(x4.x, w2.x, acc[0][0]);
            acc[0][1] = fmaf(x4.x, w2.y, acc[0][1]);
            acc[1][0] = fmaf(x4.y, w2.x, acc[1][0]);
            acc[1][1] = fmaf(x4.y, w2.y, acc[1][1]);
            acc[2][0] = fmaf(x4.z, w2.x, acc[2][0]);
            acc[2][1] = fmaf(x4.z, w2.y, acc[2][1]);
            acc[3][0] = fmaf(x4.w, w2.x, acc[3][0]);
            acc[3][1] = fmaf(x4.w, w2.y, acc[3][1]);
        }
        __syncthreads();
    }
    const int colg = by * 64 + c0;
    const float2 bb = *(const float2*)(bias + colg);
    float* Pf = ws + OFF_PF;
    #pragma unroll
    for (int i = 0; i < 4; i++) {
        const float2 out = make_float2(acc[i][0] + bb.x, acc[i][1] + bb.y);
        *(float2*)(Pf + (bx * 32 + r0 + i) * D + colg) = out;
    }
}

// ---------------------------------------------------------------------------
// K2: mega (verified R5 body) + ticket-fused out-reduction.
// Block = (nh, eg of up to 38 e).  After writing its OP partial, each block
// takes a ticket on tick[nh]; the 8th arriver ((old&7)==7 - invariant under
// any poisoned counter base) sums the 8 partials and writes outp.
// grid (64, 8) = 512 blocks, 2 blocks/CU (LDS ~61.5 KB).
// ---------------------------------------------------------------------------
__global__ __launch_bounds__(256, 2) void mega_kernel(
    const float* __restrict__ memo, float* __restrict__ ws, float* __restrict__ outp)
{
    const int nh = blockIdx.x;
    const int eg = blockIdx.y;                // 0..7
    const int e0 = eg * ECH;
    const int ecnt = (E - e0 < ECH) ? (E - e0) : ECH;   // 38 or 34
    const int n = nh >> 4, h = nh & 15;
    const int tid = threadIdx.x;
    const int lane = tid & 63;                // k
    const int w = tid >> 6;                   // 0..3

    const float* Pf = ws + OFF_PF;

    __shared__ float As[ECH * 64];            // 9.5 KB   A-chunk [e][q]
    __shared__ float Bs[64][68];              // 17.4 KB  B [k][q]; later Vs overlay
    __shared__ float U[8832];                 // 34.5 KB  union region
    __shared__ int winner;

    float* QsT = U;                           // [48][68] (d-major)
    float* KsT = U + 48 * 68;                 // [48][68]
    float* MsT = U + 2 * 48 * 68;             // [48][40]

    // ---- stage Q,K slices (transposed) + mem chunk ----
    #pragma unroll
    for (int it = 0; it < 3; it++) {
        const int idx = it * 256 + tid;       // 0..767
        const int r  = idx / 12;              // 0..63
        const int d4 = (idx % 12) * 4;
        const float4 qv = *(const float4*)(Pf + (n * QL + r) * D + h * HD + d4);
        QsT[(d4 + 0) * 68 + r] = qv.x; QsT[(d4 + 1) * 68 + r] = qv.y;
        QsT[(d4 + 2) * 68 + r] = qv.z; QsT[(d4 + 3) * 68 + r] = qv.w;
        const float4 kv = *(const float4*)(Pf + (256 + r) * D + h * HD + d4);
        KsT[(d4 + 0) * 68 + r] = kv.x; KsT[(d4 + 1) * 68 + r] = kv.y;
        KsT[(d4 + 2) * 68 + r] = kv.z; KsT[(d4 + 3) * 68 + r] = kv.w;
    }
    for (int idx = tid; idx < ecnt * 12; idx += 256) {
        const int e  = idx / 12;
        const int d4 = (idx % 12) * 4;
        const float4 mv = *(const float4*)(memo + (e0 + e) * D + h * HD + d4);
        MsT[(d4 + 0) * 40 + e] = mv.x; MsT[(d4 + 1) * 40 + e] = mv.y;
        MsT[(d4 + 2) * 40 + e] = mv.z; MsT[(d4 + 3) * 40 + e] = mv.w;
    }
    __syncthreads();

    // ---- B[k][q] = sum_d K[k,d] * Q[q,d]  (4x4 microtile) ----
    {
        const int k0 = (tid >> 4) * 4;
        const int q0 = (tid & 15) * 4;
        float acc[4][4];
        #pragma unroll
        for (int i = 0; i < 4; i++)
            #pragma unroll
            for (int j = 0; j < 4; j++) acc[i][j] = 0.f;
        #pragma unroll 4
        for (int d = 0; d < HD; d++) {
            const float4 kf = *(const float4*)&KsT[d * 68 + k0];
            const float4 qf = *(const float4*)&QsT[d * 68 + q0];
            const float kk4[4] = {kf.x, kf.y, kf.z, kf.w};
            const float qq4[4] = {qf.x, qf.y, qf.z, qf.w};
            #pragma unroll
            for (int i = 0; i < 4; i++)
                #pragma unroll
                for (int j = 0; j < 4; j++)
                    acc[i][j] = fmaf(kk4[i], qq4[j], acc[i][j]);
        }
        #pragma unroll
        for (int i = 0; i < 4; i++)
            *(float4*)&Bs[k0 + i][q0] =
                make_float4(acc[i][0], acc[i][1], acc[i][2], acc[i][3]);
    }
    // ---- A[e][q] = sum_d mem[e,d] * Q[q,d]  (3x4 microtile, guard e<ecnt) ----
    {
        const int et = (tid >> 4) * 3;        // 0..45
        const int q0 = (tid & 15) * 4;
        float acc[3][4];
        #pragma unroll
        for (int i = 0; i < 3; i++)
            #pragma unroll
            for (int j = 0; j < 4; j++) acc[i][j] = 0.f;
        #pragma unroll 4
        for (int d = 0; d < HD; d++) {
            const float me0 = MsT[d * 40 + et + 0];
            const float me1 = MsT[d * 40 + et + 1];
            const float me2 = MsT[d * 40 + et + 2];
            const float4 qf = *(const float4*)&QsT[d * 68 + q0];
            const float mm3[3] = {me0, me1, me2};
            const float qq4[4] = {qf.x, qf.y, qf.z, qf.w};
            #pragma unroll
            for (int i = 0; i < 3; i++)
                #pragma unroll
                for (int j = 0; j < 4; j++)
                    acc[i][j] = fmaf(mm3[i], qq4[j], acc[i][j]);
        }
        #pragma unroll
        for (int i = 0; i < 3; i++)
            if (et + i < ecnt)
                *(float4*)&As[(et + i) * 64 + q0] =
                    make_float4(acc[i][0], acc[i][1], acc[i][2], acc[i][3]);
    }
    __syncthreads();

    // ---- B row -> registers (lane = k) ----
    float b[64];
    #pragma unroll
    for (int j = 0; j < 16; j++)
        *(float4*)&b[j * 4] = *(const float4*)&Bs[lane][j * 4];
    __syncthreads();                          // all b[] reads done before Vs overlay

    // ---- stage V into Bs region (overlay); latency hides under e-loop ----
    float* Vs = &Bs[0][0];                    // [64][52] layout (flat, stride 52)
    #pragma unroll
    for (int it = 0; it < 3; it++) {
        const int idx = it * 256 + tid;       // 0..767
        const int k  = idx / 12;
        const int d4 = (idx % 12) * 4;
        const float4 vv = *(const float4*)(Pf + (320 + k) * D + h * HD + d4);
        *(float4*)&Vs[k * 52 + d4] = vv;
    }

    // ---- e-loop (verified core) ----
    float s[64];
    #pragma unroll
    for (int j = 0; j < 64; j++) s[j] = 0.f;

    const int eBeg = (ecnt * w) >> 2;
    const int eEnd = (ecnt * (w + 1)) >> 2;
    for (int e = eBeg; e < eEnd; e++) {
        float m[64];
        #pragma unroll
        for (int j4 = 0; j4 < 16; j4++) {
            const float4 a = *(const float4*)&As[e * 64 + j4 * 4];  // broadcast
            m[j4 * 4 + 0] = fmaxf(a.x + b[j4 * 4 + 0], 0.f);
            m[j4 * 4 + 1] = fmaxf(a.y + b[j4 * 4 + 1], 0.f);
            m[j4 * 4 + 2] = fmaxf(a.z + b[j4 * 4 + 2], 0.f);
            m[j4 * 4 + 3] = fmaxf(a.w + b[j4 * 4 + 3], 0.f);
        }
        float p0 = 0.f, p1 = 0.f, p2 = 0.f, p3 = 0.f;
        #pragma unroll
        for (int j4 = 0; j4 < 16; j4++) {
            p0 += m[j4 * 4 + 0]; p1 += m[j4 * 4 + 1];
            p2 += m[j4 * 4 + 2]; p3 += m[j4 * 4 + 3];
        }
        const float p = (p0 + p1) + (p2 + p3);
        #pragma unroll
        for (int j = 0; j < 64; j++)
            s[j] = fmaf(m[j], p, s[j]);
    }

    // ---- 4-wave tree reduce (verified) into Ss[64][68] ----
    float* r0 = U;                            // 16 KB
    float* r1 = U + 4096;                     // 16 KB
    float* Ss = U + 4096;                     // [64][68]; overlays r1 after consumed
    __syncthreads();
    if (w >= 2) {
        float* red = (w == 2) ? r0 : r1;
        #pragma unroll
        for (int q = 0; q < 64; q++) red[q * 64 + lane] = s[q];
    }
    __syncthreads();
    if (w == 0) {
        #pragma unroll
        for (int q = 0; q < 64; q++) s[q] += r0[q * 64 + lane];
    } else if (w == 1) {
        #pragma unroll
        for (int q = 0; q < 64; q++) s[q] += r1[q * 64 + lane];
    }
    __syncthreads();
    if (w == 1) {
        #pragma unroll
        for (int q = 0; q < 64; q++) r0[q * 64 + lane] = s[q];
    }
    __syncthreads();
    if (w == 0) {
        #pragma unroll
        for (int q = 0; q < 64; q++)
            Ss[q * 68 + lane] = s[q] + r0[q * 64 + lane];
    }
    __syncthreads();

    // ---- out-partial[q][48] = sum_k Ss[q][k] * Vs[k][*] ----
    {
        const int q  = tid >> 2;              // 0..63
        const int dg = tid & 3;               // 0..3 (12 d each)
        float4 a0 = make_float4(0.f, 0.f, 0.f, 0.f);
        float4 a1 = a0, a2 = a0;
        #pragma unroll 8
        for (int k = 0; k < KL; k++) {
            const float sv = Ss[q * 68 + k];
            const float4 v0 = *(const float4*)&Vs[k * 52 + dg * 12 + 0];
            const float4 v1 = *(const float4*)&Vs[k * 52 + dg * 12 + 4];
            const float4 v2 = *(const float4*)&Vs[k * 52 + dg * 12 + 8];
            a0.x = fmaf(sv, v0.x, a0.x); a0.y = fmaf(sv, v0.y, a0.y);
            a0.z = fmaf(sv, v0.z, a0.z); a0.w = fmaf(sv, v0.w, a0.w);
            a1.x = fmaf(sv, v1.x, a1.x); a1.y = fmaf(sv, v1.y, a1.y);
            a1.z = fmaf(sv, v1.z, a1.z); a1.w = fmaf(sv, v1.w, a1.w);
            a2.x = fmaf(sv, v2.x, a2.x); a2.y = fmaf(sv, v2.y, a2.y);
            a2.z = fmaf(sv, v2.z, a2.z); a2.w = fmaf(sv, v2.w, a2.w);
        }
        float* OP = ws + OFF_OP + (((eg * NH) + nh) * QL + q) * 48 + dg * 12;
        *(float4*)(OP + 0) = a0;
        *(float4*)(OP + 4) = a1;
        *(float4*)(OP + 8) = a2;
    }

    // ---- ticket: 8th eg-block for this nh folds the 8 partials -> outp ----
    __syncthreads();                          // all OP stores drained (vmcnt 0)
    if (tid == 0) {
        unsigned* tick = (unsigned*)(ws + OFF_TICK);
        const unsigned old = __hip_atomic_fetch_add(&tick[nh], 1u,
                                 __ATOMIC_ACQ_REL, __HIP_MEMORY_SCOPE_AGENT);
        // (old & 7) == 7 identifies the 8th arriver for ANY counter base value
        winner = ((old & 7u) == 7u) ? 1 : 0;
    }
    __syncthreads();
    if (winner) {
        __threadfence();                      // acquire for all waves
        const int q  = tid >> 2;              // 0..63
        const int dg = tid & 3;               // 0..3
        const float* OP = ws + OFF_OP;
        float4 a0 = make_float4(0.f, 0.f, 0.f, 0.f);
        float4 a1 = a0, a2 = a0;
        #pragma unroll
        for (int c = 0; c < NEG; c++) {
            const float* src = OP + ((c * NH + nh) * QL + q) * 48 + dg * 12;
            const float4 p0 = *(const float4*)(src + 0);
            const float4 p1 = *(const float4*)(src + 4);
            const float4 p2 = *(const float4*)(src + 8);
            a0.x += p0.x; a0.y += p0.y; a0.z += p0.z; a0.w += p0.w;
            a1.x += p1.x; a1.y += p1.y; a1.z += p1.z; a1.w += p1.w;
            a2.x += p2.x; a2.y += p2.y; a2.z += p2.z; a2.w += p2.w;
        }
        float* dst = outp + (n * QL + q) * D + h * HD + dg * 12;
        *(float4*)(dst + 0) = a0;
        *(float4*)(dst + 4) = a1;
        *(float4*)(dst + 8) = a2;
    }
}

// ---------------------------------------------------------------------------
extern "C" void kernel_launch(void* const* d_in, const int* in_sizes, int n_in,
                              void* d_out, int out_size, void* d_ws, size_t ws_size,
                              hipStream_t stream)
{
    const float* q    = (const float*)d_in[0];
    const float* k    = (const float*)d_in[1];
    const float* v    = (const float*)d_in[2];
    const float* Wq   = (const float*)d_in[3];
    const float* bq   = (const float*)d_in[4];
    const float* Wk   = (const float*)d_in[5];
    const float* bk   = (const float*)d_in[6];
    const float* Wv   = (const float*)d_in[7];
    const float* bv   = (const float*)d_in[8];
    const float* memo = (const float*)d_in[9];
    float* ws   = (float*)d_ws;
    float* outp = (float*)d_out;

    hipLaunchKernelGGL(projPf_kernel, dim3(12, 12), dim3(256), 0, stream,
                       q, k, v, Wq, Wk, Wv, bq, bk, bv, ws);
    hipLaunchKernelGGL(mega_kernel, dim3(64, NEG), dim3(256), 0, stream,
                       memo, ws, outp);
}

// Round 7
// 128.506 us; speedup vs baseline: 1.1433x; 1.1433x over previous
//
#include <hip/hip_runtime.h>

// Problem constants
#define H   16
#define E   300
#define D   768
#define HD  48
#define QL  64
#define KL  64
#define NH  64          // n(4) * h(16)
#define ROWS 384        // 256 Q rows + 64 K + 64 V
#define NEG 8           // e-chunk count
#define ECH 38          // e per mega block (last block: 34)

// Workspace float offsets
#define OFF_PF 0                              // Pf[384][768]
#define OFF_OP (ROWS*D)                       // 294,912  OP[8][nh][q][48]
// end = 1,867,776 floats = 7.5 MB

// ---------------------------------------------------------------------------
// K1: single-pass QKV projection + bias -> Pf.  BM=32, BN=64, BK=64, K=768.
// grid (12 rowblk, 12 colblk) = 144 blocks, 256 thr, 4x2 microtile.
// (verified R6 code, unchanged)
// ---------------------------------------------------------------------------
__global__ __launch_bounds__(256, 2) void projPf_kernel(
    const float* __restrict__ qin, const float* __restrict__ kin, const float* __restrict__ vin,
    const float* __restrict__ Wq, const float* __restrict__ Wk, const float* __restrict__ Wv,
    const float* __restrict__ bq, const float* __restrict__ bk, const float* __restrict__ bv,
    float* __restrict__ ws)
{
    const int bx = blockIdx.x;                // rowblk 0..11 (32 rows each)
    const int by = blockIdx.y;                // colblk 0..11 (64 cols each)

    // rowblk 0..7 -> Q, 8..9 -> K, 10..11 -> V (32-row blocks never straddle)
    const float* W    = (bx < 8) ? Wq : (bx < 10) ? Wk : Wv;
    const float* bias = (bx < 8) ? bq : (bx < 10) ? bk : bv;

    __shared__ float XsT[64][36];             // [dk][row], 36: 144B rows (16B-mult)
    __shared__ float Ws[64][64];              // [dk][col]

    const int tid = threadIdx.x;
    const int r0  = (tid >> 5) * 4;           // 0..28 (8 row-groups of 4)
    const int c0  = (tid & 31) * 2;           // 0..62 (32 col-groups of 2)

    float acc[4][2];
    #pragma unroll
    for (int i = 0; i < 4; i++) { acc[i][0] = 0.f; acc[i][1] = 0.f; }

    for (int kb = 0; kb < D; kb += 64) {
        // stage X tile (32 rows x 64 dk), transposed
        #pragma unroll
        for (int it = 0; it < 2; it++) {
            const int idx = it * 256 + tid;   // 0..511
            const int row = idx >> 4;         // 0..31
            const int d4  = (idx & 15) * 4;   // 0..60
            const int grow = bx * 32 + row;
            const float* src = (grow < 256) ? (qin + grow * D)
                             : (grow < 320) ? (kin + (grow - 256) * D)
                                            : (vin + (grow - 320) * D);
            const float4 xv = *(const float4*)(src + kb + d4);
            XsT[d4 + 0][row] = xv.x; XsT[d4 + 1][row] = xv.y;
            XsT[d4 + 2][row] = xv.z; XsT[d4 + 3][row] = xv.w;
        }
        // stage W tile (64 dk x 64 cols)
        #pragma unroll
        for (int it = 0; it < 4; it++) {
            const int idx = it * 256 + tid;   // 0..1023
            const int dk  = idx >> 4;         // 0..63
            const int c4  = (idx & 15) * 4;   // 0..60
            *(float4*)&Ws[dk][c4] =
                *(const float4*)(W + (kb + dk) * D + by * 64 + c4);
        }
        __syncthreads();
        #pragma unroll 16
        for (int dk = 0; dk < 64; dk++) {
            const float4 x4 = *(const float4*)&XsT[dk][r0];
            const float2 w2 = *(const float2*)&Ws[dk][c0];
            acc[0][0] = fmaf(x4.x, w2.x, acc[0][0]);
            acc[0][1] = fmaf(x4.x, w2.y, acc[0][1]);
            acc[1][0] = fmaf(x4.y, w2.x, acc[1][0]);
            acc[1][1] = fmaf(x4.y, w2.y, acc[1][1]);
            acc[2][0] = fmaf(x4.z, w2.x, acc[2][0]);
            acc[2][1] = fmaf(x4.z, w2.y, acc[2][1]);
            acc[3][0] = fmaf(x4.w, w2.x, acc[3][0]);
            acc[3][1] = fmaf(x4.w, w2.y, acc[3][1]);
        }
        __syncthreads();
    }
    const int colg = by * 64 + c0;
    const float2 bb = *(const float2*)(bias + colg);
    float* Pf = ws + OFF_PF;
    #pragma unroll
    for (int i = 0; i < 4; i++) {
        const float2 out = make_float2(acc[i][0] + bb.x, acc[i][1] + bb.y);
        *(float2*)(Pf + (bx * 32 + r0 + i) * D + colg) = out;
    }
}

// ---------------------------------------------------------------------------
// K2: mega (verified R5 body, ticket tail REMOVED).  Block = (nh, eg of up to
// 38 e).  Stages Q/K/mem -> builds B and A-chunk in LDS -> e-loop -> 4-wave
// tree reduce -> out-partial = Ss.V -> OP[eg][nh].
// grid (64, 8) = 512 blocks, 2 blocks/CU (LDS ~61.5 KB).
// ---------------------------------------------------------------------------
__global__ __launch_bounds__(256, 2) void mega_kernel(
    const float* __restrict__ memo, float* __restrict__ ws)
{
    const int nh = blockIdx.x;
    const int eg = blockIdx.y;                // 0..7
    const int e0 = eg * ECH;
    const int ecnt = (E - e0 < ECH) ? (E - e0) : ECH;   // 38 or 34
    const int n = nh >> 4, h = nh & 15;
    const int tid = threadIdx.x;
    const int lane = tid & 63;                // k
    const int w = tid >> 6;                   // 0..3

    const float* Pf = ws + OFF_PF;

    __shared__ float As[ECH * 64];            // 9.5 KB   A-chunk [e][q]
    __shared__ float Bs[64][68];              // 17.4 KB  B [k][q]; later Vs overlay
    __shared__ float U[8832];                 // 34.5 KB  union region

    float* QsT = U;                           // [48][68] (d-major)
    float* KsT = U + 48 * 68;                 // [48][68]
    float* MsT = U + 2 * 48 * 68;             // [48][40]

    // ---- stage Q,K slices (transposed) + mem chunk ----
    #pragma unroll
    for (int it = 0; it < 3; it++) {
        const int idx = it * 256 + tid;       // 0..767
        const int r  = idx / 12;              // 0..63
        const int d4 = (idx % 12) * 4;
        const float4 qv = *(const float4*)(Pf + (n * QL + r) * D + h * HD + d4);
        QsT[(d4 + 0) * 68 + r] = qv.x; QsT[(d4 + 1) * 68 + r] = qv.y;
        QsT[(d4 + 2) * 68 + r] = qv.z; QsT[(d4 + 3) * 68 + r] = qv.w;
        const float4 kv = *(const float4*)(Pf + (256 + r) * D + h * HD + d4);
        KsT[(d4 + 0) * 68 + r] = kv.x; KsT[(d4 + 1) * 68 + r] = kv.y;
        KsT[(d4 + 2) * 68 + r] = kv.z; KsT[(d4 + 3) * 68 + r] = kv.w;
    }
    for (int idx = tid; idx < ecnt * 12; idx += 256) {
        const int e  = idx / 12;
        const int d4 = (idx % 12) * 4;
        const float4 mv = *(const float4*)(memo + (e0 + e) * D + h * HD + d4);
        MsT[(d4 + 0) * 40 + e] = mv.x; MsT[(d4 + 1) * 40 + e] = mv.y;
        MsT[(d4 + 2) * 40 + e] = mv.z; MsT[(d4 + 3) * 40 + e] = mv.w;
    }
    __syncthreads();

    // ---- B[k][q] = sum_d K[k,d] * Q[q,d]  (4x4 microtile) ----
    {
        const int k0 = (tid >> 4) * 4;
        const int q0 = (tid & 15) * 4;
        float acc[4][4];
        #pragma unroll
        for (int i = 0; i < 4; i++)
            #pragma unroll
            for (int j = 0; j < 4; j++) acc[i][j] = 0.f;
        #pragma unroll 4
        for (int d = 0; d < HD; d++) {
            const float4 kf = *(const float4*)&KsT[d * 68 + k0];
            const float4 qf = *(const float4*)&QsT[d * 68 + q0];
            const float kk4[4] = {kf.x, kf.y, kf.z, kf.w};
            const float qq4[4] = {qf.x, qf.y, qf.z, qf.w};
            #pragma unroll
            for (int i = 0; i < 4; i++)
                #pragma unroll
                for (int j = 0; j < 4; j++)
                    acc[i][j] = fmaf(kk4[i], qq4[j], acc[i][j]);
        }
        #pragma unroll
        for (int i = 0; i < 4; i++)
            *(float4*)&Bs[k0 + i][q0] =
                make_float4(acc[i][0], acc[i][1], acc[i][2], acc[i][3]);
    }
    // ---- A[e][q] = sum_d mem[e,d] * Q[q,d]  (3x4 microtile, guard e<ecnt) ----
    {
        const int et = (tid >> 4) * 3;        // 0..45
        const int q0 = (tid & 15) * 4;
        float acc[3][4];
        #pragma unroll
        for (int i = 0; i < 3; i++)
            #pragma unroll
            for (int j = 0; j < 4; j++) acc[i][j] = 0.f;
        #pragma unroll 4
        for (int d = 0; d < HD; d++) {
            const float me0 = MsT[d * 40 + et + 0];
            const float me1 = MsT[d * 40 + et + 1];
            const float me2 = MsT[d * 40 + et + 2];
            const float4 qf = *(const float4*)&QsT[d * 68 + q0];
            const float mm3[3] = {me0, me1, me2};
            const float qq4[4] = {qf.x, qf.y, qf.z, qf.w};
            #pragma unroll
            for (int i = 0; i < 3; i++)
                #pragma unroll
                for (int j = 0; j < 4; j++)
                    acc[i][j] = fmaf(mm3[i], qq4[j], acc[i][j]);
        }
        #pragma unroll
        for (int i = 0; i < 3; i++)
            if (et + i < ecnt)
                *(float4*)&As[(et + i) * 64 + q0] =
                    make_float4(acc[i][0], acc[i][1], acc[i][2], acc[i][3]);
    }
    __syncthreads();

    // ---- B row -> registers (lane = k) ----
    float b[64];
    #pragma unroll
    for (int j = 0; j < 16; j++)
        *(float4*)&b[j * 4] = *(const float4*)&Bs[lane][j * 4];
    __syncthreads();                          // all b[] reads done before Vs overlay

    // ---- stage V into Bs region (overlay); latency hides under e-loop ----
    float* Vs = &Bs[0][0];                    // [64][52] layout (flat, stride 52)
    #pragma unroll
    for (int it = 0; it < 3; it++) {
        const int idx = it * 256 + tid;       // 0..767
        const int k  = idx / 12;
        const int d4 = (idx % 12) * 4;
        const float4 vv = *(const float4*)(Pf + (320 + k) * D + h * HD + d4);
        *(float4*)&Vs[k * 52 + d4] = vv;
    }

    // ---- e-loop (verified core) ----
    float s[64];
    #pragma unroll
    for (int j = 0; j < 64; j++) s[j] = 0.f;

    const int eBeg = (ecnt * w) >> 2;
    const int eEnd = (ecnt * (w + 1)) >> 2;
    for (int e = eBeg; e < eEnd; e++) {
        float m[64];
        #pragma unroll
        for (int j4 = 0; j4 < 16; j4++) {
            const float4 a = *(const float4*)&As[e * 64 + j4 * 4];  // broadcast
            m[j4 * 4 + 0] = fmaxf(a.x + b[j4 * 4 + 0], 0.f);
            m[j4 * 4 + 1] = fmaxf(a.y + b[j4 * 4 + 1], 0.f);
            m[j4 * 4 + 2] = fmaxf(a.z + b[j4 * 4 + 2], 0.f);
            m[j4 * 4 + 3] = fmaxf(a.w + b[j4 * 4 + 3], 0.f);
        }
        float p0 = 0.f, p1 = 0.f, p2 = 0.f, p3 = 0.f;
        #pragma unroll
        for (int j4 = 0; j4 < 16; j4++) {
            p0 += m[j4 * 4 + 0]; p1 += m[j4 * 4 + 1];
            p2 += m[j4 * 4 + 2]; p3 += m[j4 * 4 + 3];
        }
        const float p = (p0 + p1) + (p2 + p3);
        #pragma unroll
        for (int j = 0; j < 64; j++)
            s[j] = fmaf(m[j], p, s[j]);
    }

    // ---- 4-wave tree reduce (verified) into Ss[64][68] ----
    float* r0 = U;                            // 16 KB
    float* r1 = U + 4096;                     // 16 KB
    float* Ss = U + 4096;                     // [64][68]; overlays r1 after consumed
    __syncthreads();
    if (w >= 2) {
        float* red = (w == 2) ? r0 : r1;
        #pragma unroll
        for (int q = 0; q < 64; q++) red[q * 64 + lane] = s[q];
    }
    __syncthreads();
    if (w == 0) {
        #pragma unroll
        for (int q = 0; q < 64; q++) s[q] += r0[q * 64 + lane];
    } else if (w == 1) {
        #pragma unroll
        for (int q = 0; q < 64; q++) s[q] += r1[q * 64 + lane];
    }
    __syncthreads();
    if (w == 1) {
        #pragma unroll
        for (int q = 0; q < 64; q++) r0[q * 64 + lane] = s[q];
    }
    __syncthreads();
    if (w == 0) {
        #pragma unroll
        for (int q = 0; q < 64; q++)
            Ss[q * 68 + lane] = s[q] + r0[q * 64 + lane];
    }
    __syncthreads();

    // ---- out-partial[q][48] = sum_k Ss[q][k] * Vs[k][*] ----
    {
        const int q  = tid >> 2;              // 0..63
        const int dg = tid & 3;               // 0..3 (12 d each)
        float4 a0 = make_float4(0.f, 0.f, 0.f, 0.f);
        float4 a1 = a0, a2 = a0;
        #pragma unroll 8
        for (int k = 0; k < KL; k++) {
            const float sv = Ss[q * 68 + k];
            const float4 v0 = *(const float4*)&Vs[k * 52 + dg * 12 + 0];
            const float4 v1 = *(const float4*)&Vs[k * 52 + dg * 12 + 4];
            const float4 v2 = *(const float4*)&Vs[k * 52 + dg * 12 + 8];
            a0.x = fmaf(sv, v0.x, a0.x); a0.y = fmaf(sv, v0.y, a0.y);
            a0.z = fmaf(sv, v0.z, a0.z); a0.w = fmaf(sv, v0.w, a0.w);
            a1.x = fmaf(sv, v1.x, a1.x); a1.y = fmaf(sv, v1.y, a1.y);
            a1.z = fmaf(sv, v1.z, a1.z); a1.w = fmaf(sv, v1.w, a1.w);
            a2.x = fmaf(sv, v2.x, a2.x); a2.y = fmaf(sv, v2.y, a2.y);
            a2.z = fmaf(sv, v2.z, a2.z); a2.w = fmaf(sv, v2.w, a2.w);
        }
        float* OP = ws + OFF_OP + (((eg * NH) + nh) * QL + q) * 48 + dg * 12;
        *(float4*)(OP + 0) = a0;
        *(float4*)(OP + 4) = a1;
        *(float4*)(OP + 8) = a2;
    }
}

// ---------------------------------------------------------------------------
// K3: out = sum of 8 out-partials.  grid 192 x 256, one float4/thread.
// (verified R5 code, unchanged)
// ---------------------------------------------------------------------------
__global__ __launch_bounds__(256) void outsum_kernel(
    const float* __restrict__ ws_c, float* __restrict__ outp)
{
    const int g = blockIdx.x * 256 + threadIdx.x;   // 0..49151
    const int d12 = g % 12;
    const int q   = (g / 12) & 63;
    const int nh  = g / 768;                        // 0..63
    const int n = nh >> 4, h = nh & 15;
    const float* OP = ws_c + OFF_OP;

    float4 acc = make_float4(0.f, 0.f, 0.f, 0.f);
    #pragma unroll
    for (int c = 0; c < NEG; c++) {
        const float4 p = *(const float4*)(OP + c * (NH * QL * 48)
                                          + (nh * QL + q) * 48 + d12 * 4);
        acc.x += p.x; acc.y += p.y; acc.z += p.z; acc.w += p.w;
    }
    *(float4*)(outp + (n * QL + q) * D + h * HD + d12 * 4) = acc;
}

// ---------------------------------------------------------------------------
extern "C" void kernel_launch(void* const* d_in, const int* in_sizes, int n_in,
                              void* d_out, int out_size, void* d_ws, size_t ws_size,
                              hipStream_t stream)
{
    const float* q    = (const float*)d_in[0];
    const float* k    = (const float*)d_in[1];
    const float* v    = (const float*)d_in[2];
    const float* Wq   = (const float*)d_in[3];
    const float* bq   = (const float*)d_in[4];
    const float* Wk   = (const float*)d_in[5];
    const float* bk   = (const float*)d_in[6];
    const float* Wv   = (const float*)d_in[7];
    const float* bv   = (const float*)d_in[8];
    const float* memo = (const float*)d_in[9];
    float* ws   = (float*)d_ws;
    float* outp = (float*)d_out;

    hipLaunchKernelGGL(projPf_kernel, dim3(12, 12), dim3(256), 0, stream,
                       q, k, v, Wq, Wk, Wv, bq, bk, bv, ws);
    hipLaunchKernelGGL(mega_kernel, dim3(64, NEG), dim3(256), 0, stream, memo, ws);
    hipLaunchKernelGGL(outsum_kernel, dim3(192), dim3(256), 0, stream, ws, outp);
}